// Round 11
// baseline (49.546 us; speedup 1.0000x reference)
//
#include <hip/hip_runtime.h>
#include <stdint.h>

#define NEGV (-1e30f)

constexpr int L1_ = 512;
constexpr int H_  = 128;
constexpr int NK_ = 2048;   // 32 turns * 64 tokens

typedef __attribute__((ext_vector_type(8))) _Float16 f16x8;
typedef __attribute__((ext_vector_type(2))) __fp16   h16x2;
typedef __attribute__((ext_vector_type(4))) float    f32x4;

static __device__ __forceinline__ uint16_t f2h(float x) {
    union { _Float16 h; uint16_t u; } cv; cv.h = (_Float16)x; return cv.u;
}

static __device__ __forceinline__ void gload16(const void* g, void* l) {
    __builtin_amdgcn_global_load_lds(
        (const __attribute__((address_space(1))) uint32_t*)g,
        (__attribute__((address_space(3))) uint32_t*)l, 16, 0, 0);
}

// Fragment-major layouts (16B chunk per lane, lane = (g<<4)|n16):
//  Y2[kt(32)][kkT(4)][ks(4)][lane]  chunk = yp[kt*64+kkT*16+n16][ks*32+g*8 .. +8]
//  V2[kt(32)][cT(8)][ks(2)][lane]   chunk = dlg[kt*64+ks*32+g*8+j][cT*16+n16]
//  W2[cT(8)][ks(4)][lane]           chunk = W [cT*16+n16][ks*32+g*8 .. +8]

// ---------------------------------------------------------------------------
// Preprocessing, 256 threads/block (unchanged):
// ---------------------------------------------------------------------------
__global__ __launch_bounds__(256) void preproc_kernel(
        const float* __restrict__ xq,
        const float* __restrict__ xa,
        const float* __restrict__ W,
        const float* __restrict__ bias,
        const uint8_t* __restrict__ qm,
        const uint8_t* __restrict__ am,
        uint8_t* __restrict__ Y2,
        uint8_t* __restrict__ V2,
        uint8_t* __restrict__ W2,
        float* __restrict__ badd) {
    int b = blockIdx.x;
    int tid = threadIdx.x;
    __shared__ __align__(16) float sbuf[64 * 128];   // 32 KB

    if (b < 128) {
        int k0 = b * 16;
        f32x4* xr4 = (f32x4*)sbuf;
#pragma unroll
        for (int i = 0; i < 2; ++i) {
            int idx = tid + i * 256;
            int row = idx >> 5, d4 = idx & 31;
            int k = k0 + row;
            int b2 = k >> 6, r = k & 63;
            const float* src = (r < 32) ? (xq + (size_t)(b2 * 32 + r) * H_)
                                        : (xa + (size_t)(b2 * 32 + (r - 32)) * H_);
            xr4[idx] = *(const f32x4*)(src + d4 * 4);
        }
        __syncthreads();
        int c = tid & 127, rh = tid >> 7;
        float acc[8];
#pragma unroll
        for (int i = 0; i < 8; ++i) acc[i] = 0.0f;
        const f32x4* w4 = (const f32x4*)(W + (size_t)c * H_);
        for (int d4 = 0; d4 < 32; ++d4) {
            f32x4 wv = w4[d4];
#pragma unroll
            for (int i = 0; i < 8; ++i) {
                f32x4 x = xr4[(rh * 8 + i) * 32 + d4];
                acc[i] += wv[0]*x[0] + wv[1]*x[1] + wv[2]*x[2] + wv[3]*x[3];
            }
        }
        float bc = bias[c];
        float* res = sbuf + 2048;
#pragma unroll
        for (int i = 0; i < 8; ++i)
            res[(rh * 8 + i) * H_ + c] = fmaxf(acc[i] + bc, 0.0f);
        __syncthreads();
        int ks = tid >> 6, l = tid & 63, n16 = l & 15, g = l >> 4;
        uint16_t hbuf[8];
#pragma unroll
        for (int j = 0; j < 8; ++j)
            hbuf[j] = f2h(res[n16 * H_ + ks * 32 + g * 8 + j]);
        uint8_t* dst = Y2 + (((size_t)b * 4 + ks) << 10) + l * 16;
        *(uint64_t*)dst       = ((const uint64_t*)hbuf)[0];
        *(uint64_t*)(dst + 8) = ((const uint64_t*)hbuf)[1];
    } else if (b < 160) {
        int kt = b - 128;
        f32x4* ld4 = (f32x4*)sbuf;
#pragma unroll
        for (int i = 0; i < 8; ++i) {
            int idx = tid + i * 256;
            int row = idx >> 5, d4 = idx & 31;
            const float* src = (row < 32) ? (xq + (size_t)(kt * 32 + row) * H_)
                                          : (xa + (size_t)(kt * 32 + row - 32) * H_);
            ld4[idx] = *(const f32x4*)(src + d4 * 4);
        }
        __syncthreads();
#pragma unroll
        for (int i = 0; i < 4; ++i) {
            int id = tid + i * 256;
            int cT = id >> 7, ks = (id >> 6) & 1, l = id & 63;
            int n16 = l & 15, g = l >> 4;
            uint16_t hbuf[8];
#pragma unroll
            for (int j = 0; j < 8; ++j)
                hbuf[j] = f2h(sbuf[(ks * 32 + g * 8 + j) * H_ + cT * 16 + n16]);
            uint8_t* dst = V2 + (((size_t)kt * 16 + cT * 2 + ks) << 10) + l * 16;
            *(uint64_t*)dst       = ((const uint64_t*)hbuf)[0];
            *(uint64_t*)(dst + 8) = ((const uint64_t*)hbuf)[1];
        }
    } else if (b == 160) {
        int* flags = (int*)sbuf;
        if (tid == 0) { flags[0] = 0; flags[1] = 0; }
        __syncthreads();
        uint32_t v = ((const uint32_t*)qm)[tid] | ((const uint32_t*)am)[tid];
        if (v & 0xFFu)        atomicOr(&flags[0], 1);
        if (v & 0xFFFFFF00u)  atomicOr(&flags[1], 1);
        __syncthreads();
        int f0 = flags[0], f1 = flags[1];
        int mode = (f0 && !f1) ? 0 : ((!f0 && f1) ? 1 : 2);
        for (int k = tid; k < NK_; k += 256) {
            int b2 = k >> 6, r = k & 63;
            int idx = b2 * 32 + (r < 32 ? r : r - 32);
            const uint8_t* src = (r < 32) ? qm : am;
            int p;
            if (mode == 0)      p = (((const int*)src)[idx] != 0);
            else if (mode == 1) p = (((const float*)src)[idx] != 0.0f);
            else                p = (src[idx] != 0);
            badd[k] = p ? NEGV : 0.0f;
        }
    } else {
        for (int h = 0; h < 2; ++h) {
            f32x4* s4 = (f32x4*)sbuf;
#pragma unroll
            for (int i = 0; i < 8; ++i) {
                int idx = tid + i * 256;
                s4[idx] = *(const f32x4*)(W + (size_t)h * 64 * H_ + idx * 4);
            }
            __syncthreads();
#pragma unroll
            for (int i = 0; i < 4; ++i) {
                int id = tid + i * 256;
                int ct = id >> 8, ks = (id >> 6) & 3, l = id & 63;
                int n16 = l & 15, g = l >> 4;
                uint16_t hb[8];
#pragma unroll
                for (int j = 0; j < 8; ++j)
                    hb[j] = f2h(sbuf[(ct * 16 + n16) * H_ + ks * 32 + g * 8 + j]);
                uint8_t* dst = W2 + (((size_t)((h * 4 + ct) * 4 + ks)) << 10) + l * 16;
                *(uint64_t*)dst       = ((const uint64_t*)hb)[0];
                *(uint64_t*)(dst + 8) = ((const uint64_t*)hb)[1];
            }
            __syncthreads();
        }
    }
}

// ---------------------------------------------------------------------------
// Flash attention: 512 thr / 8 waves / 64 l-rows. Wave (rg=w&3, kh=w>>2):
// 16 rows, k-stride 2. Per round (2 k-tiles): global_load_lds-stage next
// round's Y+V (64KB) early; compute from current LDS buffers; one barrier.
// LDS: R0@0 (64K), R1@64K (64K), P/xpbuf@128K (16K). Obuf overlays R0 at end.
// ---------------------------------------------------------------------------
__global__ __launch_bounds__(512, 1) void attn_kernel(
        const float*   __restrict__ xd,
        const uint8_t* __restrict__ W2,
        const float*   __restrict__ bias,
        const uint8_t* __restrict__ Y2,
        const uint8_t* __restrict__ V2,
        const float*   __restrict__ badd,
        const float*   __restrict__ rw,
        float* __restrict__ out) {
    int bid = blockIdx.x;
    int t  = bid >> 3;
    int l0 = (bid & 7) << 6;       // 64 rows
    int tid = threadIdx.x;

    __shared__ __align__(16) char LDSA[147456];
    __shared__ float stats_m[8][16];
    __shared__ float stats_l[8][16];

    if (t == 0) {                  // zero_first
        f32x4 z = {0.f, 0.f, 0.f, 0.f};
        f32x4* o4 = (f32x4*)(out + (size_t)l0 * H_);
        for (int i = tid; i < 64 * H_ / 4; i += 512) o4[i] = z;
        return;
    }

    int w = tid >> 6, lane = tid & 63, n16 = lane & 15, g = lane >> 4;
    int rg = w & 3, kh = w >> 2;
    int swz = (n16 & 7) << 4;

    // ---- stage round 0 (kt 0,1) into R0 — earliest possible
    {
        char* ld = LDSA;
        gload16(Y2 + tid * 16,        ld + tid * 16);
        gload16(Y2 + tid * 16 + 8192, ld + tid * 16 + 8192);
        gload16(V2 + tid * 16,         ld + 16384 + tid * 16);
        gload16(V2 + tid * 16 + 8192,  ld + 24576 + tid * 16);
        if (1 < t) {
            const uint8_t* gy = Y2 + (1 << 14);
            const uint8_t* gv = V2 + (1 << 14);
            char* ld2 = LDSA + 32768;
            gload16(gy + tid * 16,        ld2 + tid * 16);
            gload16(gy + tid * 16 + 8192, ld2 + tid * 16 + 8192);
            gload16(gv + tid * 16,         ld2 + 16384 + tid * 16);
            gload16(gv + tid * 16 + 8192,  ld2 + 24576 + tid * 16);
        }
    }

    // ---- prologue: fused x-projection (wave: rows rg*16.., cols kh*64..)
    char* xbuf  = LDSA + 65536;    // 64 x 256B fp16 swizzled (R1 region, dead before R1 staged)
    char* xpbuf = LDSA + 131072;   // 64 x 256B fp16 swizzled (P region)
    {
        const float* xsrc = xd + (size_t)(t * L1_ + l0) * H_;
#pragma unroll
        for (int i = 0; i < 4; ++i) {
            int idx = tid + i * 512;          // 2048 f32x4
            int row = idx >> 5, c4 = idx & 31;
            f32x4 v = *(const f32x4*)(xsrc + idx * 4);
            uint16_t hb[4] = { f2h(v[0]), f2h(v[1]), f2h(v[2]), f2h(v[3]) };
            *(uint64_t*)(xbuf + row * 256 + ((c4 * 8) ^ ((row & 7) << 4))) = *(const uint64_t*)hb;
        }
    }
    __syncthreads();
    {
        f16x8 af[4];
        int arow = rg * 16 + n16;
#pragma unroll
        for (int ks = 0; ks < 4; ++ks)
            af[ks] = *(const f16x8*)(xbuf + arow * 256 + ((ks * 64 + g * 16) ^ swz));
        f32x4 z4 = {0.f, 0.f, 0.f, 0.f};
        f32x4 d[4] = {z4, z4, z4, z4};
#pragma unroll
        for (int c = 0; c < 4; ++c)
#pragma unroll
            for (int ks = 0; ks < 4; ++ks) {
                f16x8 wf = *(const f16x8*)(W2 + (((size_t)(kh * 4 + c) * 4 + ks) << 10) + lane * 16);
                d[c] = __builtin_amdgcn_mfma_f32_16x16x32_f16(af[ks], wf, d[c], 0, 0, 0);
            }
#pragma unroll
        for (int c = 0; c < 4; ++c) {
            int col = (kh * 4 + c) * 16 + n16;
            float bb = bias[col];
#pragma unroll
            for (int q = 0; q < 4; ++q) {
                int row2 = rg * 16 + g * 4 + q;
                *(uint16_t*)(xpbuf + row2 * 256 + ((col * 2) ^ ((row2 & 7) << 4)))
                    = f2h(fmaxf(d[c][q] + bb, 0.0f));
            }
        }
    }
    __syncthreads();
    f16x8 xf[4];
    {
        int arow = rg * 16 + n16;
#pragma unroll
        for (int ks = 0; ks < 4; ++ks)
            xf[ks] = *(const f16x8*)(xpbuf + arow * 256 + ((ks * 64 + g * 16) ^ swz));
    }
    __syncthreads();   // everyone done with xpbuf before P overwrites it

    // ---- main loop over rounds
    f32x4 zero4 = {0.f, 0.f, 0.f, 0.f};
    f32x4 acc[8];
#pragma unroll
    for (int c = 0; c < 8; ++c) acc[c] = zero4;
    float m_r = -INFINITY, l_r = 0.0f;
    float rww = rw[0];
    char* Pw = LDSA + 131072 + w * 2048;   // 16 rows x 128B per wave
    int nR = (t + 1) >> 1;

    for (int i = 0; i < nR; ++i) {
        int cur = i & 1;
        // ---- stage round i+1 (async; drained by this round's end barrier)
        if (i + 1 < nR) {
            int kt0 = 2 * (i + 1);
            char* ld = LDSA + (cur ? 0 : 65536);
            const uint8_t* gy = Y2 + ((size_t)kt0 << 14);
            const uint8_t* gv = V2 + ((size_t)kt0 << 14);
            gload16(gy + tid * 16,        ld + tid * 16);
            gload16(gy + tid * 16 + 8192, ld + tid * 16 + 8192);
            gload16(gv + tid * 16,         ld + 16384 + tid * 16);
            gload16(gv + tid * 16 + 8192,  ld + 24576 + tid * 16);
            if (kt0 + 1 < t) {
                gy += (1 << 14); gv += (1 << 14);
                char* ld2 = ld + 32768;
                gload16(gy + tid * 16,        ld2 + tid * 16);
                gload16(gy + tid * 16 + 8192, ld2 + tid * 16 + 8192);
                gload16(gv + tid * 16,         ld2 + 16384 + tid * 16);
                gload16(gv + tid * 16 + 8192,  ld2 + 24576 + tid * 16);
            }
        }

        int kt = 2 * i + kh;
        if (kt < t) {
            const char* Yb = LDSA + (cur ? 65536 : 0) + kh * 32768;
            const char* Vb = Yb + 16384;

            // ---- S^T: 16 MFMAs from LDS fragments
            f32x4 ss[4];
#pragma unroll
            for (int kkT = 0; kkT < 4; ++kkT) ss[kkT] = zero4;
            __builtin_amdgcn_s_setprio(1);
#pragma unroll
            for (int ks = 0; ks < 4; ++ks) {
                f16x8 yf[4];
#pragma unroll
                for (int kkT = 0; kkT < 4; ++kkT)
                    yf[kkT] = *(const f16x8*)(Yb + ((kkT * 4 + ks) << 10) + lane * 16);
#pragma unroll
                for (int kkT = 0; kkT < 4; ++kkT)
                    ss[kkT] = __builtin_amdgcn_mfma_f32_16x16x32_f16(yf[kkT], xf[ks], ss[kkT], 0, 0, 0);
            }
            __builtin_amdgcn_s_setprio(0);

            // ---- mask + recency bias
            float biasK = rww * (float)(t - kt);
#pragma unroll
            for (int kkT = 0; kkT < 4; ++kkT) {
                f32x4 ba = *(const f32x4*)(badd + kt * 64 + kkT * 16 + g * 4);
                ss[kkT] += (ba + biasK);
            }

            // ---- online max (16 in-lane + cross-g shfl)
            f32x4 mx4 = ss[0];
#pragma unroll
            for (int kkT = 1; kkT < 4; ++kkT) {
                mx4[0] = fmaxf(mx4[0], ss[kkT][0]);
                mx4[1] = fmaxf(mx4[1], ss[kkT][1]);
                mx4[2] = fmaxf(mx4[2], ss[kkT][2]);
                mx4[3] = fmaxf(mx4[3], ss[kkT][3]);
            }
            float mx = fmaxf(fmaxf(mx4[0], mx4[1]), fmaxf(mx4[2], mx4[3]));
            mx = fmaxf(mx, __shfl_xor(mx, 16));
            mx = fmaxf(mx, __shfl_xor(mx, 32));
            float mn = fmaxf(m_r, mx);
            float sc = __expf(m_r - mn);
            m_r = mn;

            // ---- P = exp(s-m), write to wave-private LDS, running sum
            float ps = 0.0f;
#pragma unroll
            for (int kkT = 0; kkT < 4; ++kkT) {
                f32x4 p;
#pragma unroll
                for (int q = 0; q < 4; ++q) p[q] = __expf(ss[kkT][q] - mn);
                ps += (p[0] + p[1]) + (p[2] + p[3]);
                union { h16x2 h2[2]; uint64_t u64; } pk;
                pk.h2[0] = __builtin_amdgcn_cvt_pkrtz(p[0], p[1]);
                pk.h2[1] = __builtin_amdgcn_cvt_pkrtz(p[2], p[3]);
                *(uint64_t*)(Pw + n16 * 128 + ((kkT * 32 + g * 8) ^ swz)) = pk.u64;
            }
            ps += __shfl_xor(ps, 16);
            ps += __shfl_xor(ps, 32);
            l_r = l_r * sc + ps;

            asm volatile("s_waitcnt lgkmcnt(0)" ::: "memory");

            // ---- rescale O (skip when max unchanged)
            if (!__all(sc == 1.0f)) {
                f32x4 s4;
#pragma unroll
                for (int q = 0; q < 4; ++q) s4[q] = __shfl(sc, (g << 2) + q);
#pragma unroll
                for (int c = 0; c < 8; ++c) acc[c] *= s4;
            }

            // ---- PV: 16 MFMAs, V from LDS
            f16x8 pa0 = *(const f16x8*)(Pw + n16 * 128 + ((g * 16) ^ swz));
            f16x8 pa1 = *(const f16x8*)(Pw + n16 * 128 + ((64 + g * 16) ^ swz));
            __builtin_amdgcn_s_setprio(1);
#pragma unroll
            for (int cT = 0; cT < 8; ++cT) {
                f16x8 vb0 = *(const f16x8*)(Vb + ((cT * 2) << 10) + lane * 16);
                f16x8 vb1 = *(const f16x8*)(Vb + ((cT * 2 + 1) << 10) + lane * 16);
                acc[cT] = __builtin_amdgcn_mfma_f32_16x16x32_f16(pa0, vb0, acc[cT], 0, 0, 0);
                acc[cT] = __builtin_amdgcn_mfma_f32_16x16x32_f16(pa1, vb1, acc[cT], 0, 0, 0);
            }
            __builtin_amdgcn_s_setprio(0);
        }
        __syncthreads();   // publishes next round's buffers, retires current
    }

    // ---- combine kh-pair stats, write output
    if (g == 0) { stats_m[w][n16] = m_r; stats_l[w][n16] = l_r; }
    __syncthreads();

    int pw = w ^ 4;
    float fac[4];
#pragma unroll
    for (int q = 0; q < 4; ++q) {
        int r = (g << 2) + q;
        float ma = stats_m[w][r],  mb = stats_m[pw][r];
        float la = stats_l[w][r],  lb = stats_l[pw][r];
        float mf = fmaxf(ma, mb);
        float lf = la * __expf(ma - mf) + lb * __expf(mb - mf);
        fac[q] = __expf(ma - mf) / lf;
    }

    float* Ob = (float*)LDSA;      // [4 rg][16 row][128 col] f32 = 32 KB (stage region free)
    if (kh == 1) {
#pragma unroll
        for (int cT = 0; cT < 8; ++cT)
#pragma unroll
            for (int q = 0; q < 4; ++q)
                Ob[(rg * 16 + g * 4 + q) * 128 + cT * 16 + n16] = acc[cT][q] * fac[q];
    }
    __syncthreads();
    if (kh == 0) {
        size_t ob = (size_t)(t * L1_ + l0 + rg * 16) * H_;
#pragma unroll
        for (int cT = 0; cT < 8; ++cT)
#pragma unroll
            for (int q = 0; q < 4; ++q) {
                float v = acc[cT][q] * fac[q]
                        + Ob[(rg * 16 + g * 4 + q) * 128 + cT * 16 + n16];
                out[ob + (size_t)(g * 4 + q) * H_ + cT * 16 + n16] = v;
            }
    }
}

// ---------------------------------------------------------------------------
extern "C" void kernel_launch(void* const* d_in, const int* in_sizes, int n_in,
                              void* d_out, int out_size, void* d_ws, size_t ws_size,
                              hipStream_t stream) {
    const float*   xd   = (const float*)d_in[0];
    const float*   xq   = (const float*)d_in[1];
    const float*   xa   = (const float*)d_in[2];
    const float*   W    = (const float*)d_in[3];
    const float*   bias = (const float*)d_in[4];
    const float*   rw   = (const float*)d_in[5];
    const uint8_t* qm   = (const uint8_t*)d_in[6];
    const uint8_t* am   = (const uint8_t*)d_in[7];
    float* out = (float*)d_out;

    char* ws = (char*)d_ws;
    float*   badd = (float*)ws;                          // 8 KB
    uint8_t* Y2   = (uint8_t*)(ws + 8192);               // 512 KB
    uint8_t* V2   = (uint8_t*)(ws + 8192 + 524288);      // 512 KB
    uint8_t* W2   = (uint8_t*)(ws + 8192 + 2 * 524288);  // 32 KB

    preproc_kernel<<<162, 256, 0, stream>>>(xq, xa, W, bias, qm, am,
                                            Y2, V2, W2, badd);
    attn_kernel<<<256, 512, 0, stream>>>(xd, W2, bias, Y2, V2, badd, rw, out);
}